// Round 6
// baseline (121.148 us; speedup 1.0000x reference)
//
#include <hip/hip_runtime.h>

#define NN 8192      // nodes
#define NE 262144    // edges
#define DIM 128
#define BCAP 128     // bucket capacity (deg ~ Poisson(32); P(deg>128) ~ 0)

typedef float f32x4 __attribute__((ext_vector_type(4)));

__device__ __forceinline__ float4 f4fma(float s, float4 w, float4 acc) {
    acc.x = fmaf(s, w.x, acc.x);
    acc.y = fmaf(s, w.y, acc.y);
    acc.z = fmaf(s, w.z, acc.z);
    acc.w = fmaf(s, w.w, acc.w);
    return acc;
}
__device__ __forceinline__ float f4dot(float4 a, float4 b) {
    return fmaf(a.x, b.x, fmaf(a.y, b.y, fmaf(a.z, b.z, a.w * b.w)));
}

// ---------------- K1: zero cnt (blocks 0..31) + u/v/beta (block 32) ----------------
__global__ __launch_bounds__(256) void init_kernel(const float* __restrict__ Wout,
                                                   const float* __restrict__ bout,
                                                   const float* __restrict__ we,
                                                   const float* __restrict__ bedge,
                                                   int* __restrict__ cnt,
                                                   float* __restrict__ u,
                                                   float* __restrict__ v,
                                                   float* __restrict__ beta) {
    int k = threadIdx.x;
    if (blockIdx.x < 32) {
        cnt[blockIdx.x * 256 + k] = 0;
        return;
    }
    if (k < DIM) {
        const float4* W4 = (const float4*)(Wout + (k << 7));
        const float4* we4 = (const float4*)we;
        float su = 0.f, sv = 0.f;
#pragma unroll
        for (int j = 0; j < 32; ++j) {
            float4 w = W4[j];
            su += f4dot(w, we4[j]);
            sv += f4dot(w, we4[32 + j]);
        }
        u[k] = su;
        v[k] = sv;
    }
    __shared__ float red[256];
    red[k] = (k < DIM) ? bout[k] * we[k] : 0.f;
    __syncthreads();
    for (int off = 128; off >= 1; off >>= 1) {
        if (k < off) red[k] += red[k + off];
        __syncthreads();
    }
    float b0 = red[0];
    __syncthreads();
    red[k] = (k < DIM) ? bout[k] * we[DIM + k] : 0.f;
    __syncthreads();
    for (int off = 128; off >= 1; off >>= 1) {
        if (k < off) red[k] += red[k + off];
        __syncthreads();
    }
    if (k == 0) {
        beta[0] = b0 + bedge[0];
        beta[1] = red[0];
    }
}

// ---------------- K2: scatter edges into buckets; cnt ends as indegree ----------------
__global__ __launch_bounds__(256) void scatter_kernel(const int* __restrict__ src,
                                                      const int* __restrict__ dst,
                                                      int* __restrict__ cnt,
                                                      int* __restrict__ bucket) {
    int e = blockIdx.x * 256 + threadIdx.x;
    int d = dst[e];
    int p = atomicAdd(&cnt[d], 1);
    if (p < BCAP) bucket[(d << 7) + p] = src[e];
}

// ---------------- F1: G1[r] = (x @ W1)[r] * dinv[r] ----------------
__global__ __launch_bounds__(256) void gemm_pre(const float* __restrict__ X,
                                                const float* __restrict__ W,
                                                const int* __restrict__ cnt,
                                                float* __restrict__ G) {
    __shared__ float4 Wl[128 * 32];
    __shared__ float4 Xl[32 * 32];
    int tid = threadIdx.x;
    int rbase = blockIdx.x * 32;

    const float4* W4 = (const float4*)W;
#pragma unroll
    for (int i = 0; i < 16; ++i) Wl[i * 256 + tid] = W4[i * 256 + tid];
    const float4* X4 = (const float4*)(X + rbase * DIM);
#pragma unroll
    for (int i = 0; i < 4; ++i) Xl[i * 256 + tid] = X4[i * 256 + tid];
    __syncthreads();

    int tx = tid & 31;
    int ty = tid >> 5;
    float4 acc[4];
#pragma unroll
    for (int i = 0; i < 4; ++i) acc[i] = make_float4(0.f, 0.f, 0.f, 0.f);

    for (int k4 = 0; k4 < 32; ++k4) {
        float4 w0 = Wl[(k4 * 4 + 0) * 32 + tx];
        float4 w1 = Wl[(k4 * 4 + 1) * 32 + tx];
        float4 w2 = Wl[(k4 * 4 + 2) * 32 + tx];
        float4 w3 = Wl[(k4 * 4 + 3) * 32 + tx];
#pragma unroll
        for (int i = 0; i < 4; ++i) {
            float4 xv = Xl[(ty * 4 + i) * 32 + k4];
            acc[i] = f4fma(xv.x, w0, acc[i]);
            acc[i] = f4fma(xv.y, w1, acc[i]);
            acc[i] = f4fma(xv.z, w2, acc[i]);
            acc[i] = f4fma(xv.w, w3, acc[i]);
        }
    }

    float4* G4 = (float4*)G;
#pragma unroll
    for (int i = 0; i < 4; ++i) {
        int r = rbase + ty * 4 + i;
        float dv = rsqrtf((float)(cnt[r] + 1));
        float4 o = acc[i];
        o.x *= dv; o.y *= dv; o.z *= dv; o.w *= dv;
        G4[r * 32 + tx] = o;
    }
}

// ---------------- F2: fused agg(G1) -> S2 in LDS -> GEMM with W2 -> raw G2 ----------------
// 4 waves x 8 nodes = 32 rows per block (must cover the whole GEMM tile!)
__global__ __launch_bounds__(256) void agg_gemm(const float* __restrict__ G1,
                                                const int* __restrict__ cnt,
                                                const int* __restrict__ bucket,
                                                const float* __restrict__ b1,
                                                const float* __restrict__ W2,
                                                float* __restrict__ G2) {
    __shared__ float4 Wl[128 * 32];
    __shared__ float4 Xl[32 * 32];
    int tid = threadIdx.x;
    int rbase = blockIdx.x * 32;
    int w = tid >> 6;
    int lane = tid & 63;

    // phase B setup: this wave owns nodes rbase + w*8 + j, j=0..7
    const float2* G12 = (const float2*)G1;
    int deg[8], i0[8], i1[8];
    float dv[8];
    float2 acc[8];
    int nb = rbase + w * 8;
#pragma unroll
    for (int j = 0; j < 8; ++j) {
        int n = nb + j;
        deg[j] = cnt[n];
        dv[j] = rsqrtf((float)(deg[j] + 1));
        i0[j] = bucket[(n << 7) + lane];
        i1[j] = bucket[(n << 7) + 64 + lane];
        acc[j] = G12[n * 64 + lane];  // self term
    }

    // phase A: W2 -> LDS (overlaps with index-load latency)
    const float4* W4 = (const float4*)W2;
#pragma unroll
    for (int i = 0; i < 16; ++i) Wl[i * 256 + tid] = W4[i * 256 + tid];

    int m = max(max(max(deg[0], deg[1]), max(deg[2], deg[3])),
                max(max(deg[4], deg[5]), max(deg[6], deg[7])));
    for (int e = 0; e < m; ++e) {
        int lo = e & 63;
        bool hi = e >= 64;
#pragma unroll
        for (int j = 0; j < 8; ++j) {
            int s = __shfl(hi ? i1[j] : i0[j], lo);
            bool val = e < deg[j];
            s = val ? s : 0;          // bucket tail is poison — never use as addr
            float wt = val ? 1.f : 0.f;
            float2 t = G12[s * 64 + lane];
            acc[j].x = fmaf(t.x, wt, acc[j].x);
            acc[j].y = fmaf(t.y, wt, acc[j].y);
        }
    }

    // elementwise: S2 = dv * relu(dv*Y1 + b1) -> Xl rows w*8..w*8+7
    const float2* B2 = (const float2*)b1;
    float2 bb = B2[lane];
    float2* Xl2 = (float2*)Xl;
#pragma unroll
    for (int j = 0; j < 8; ++j) {
        float2 o;
        o.x = fmaxf(fmaf(acc[j].x, dv[j], bb.x), 0.f) * dv[j];
        o.y = fmaxf(fmaf(acc[j].y, dv[j], bb.y), 0.f) * dv[j];
        Xl2[(w * 8 + j) * 64 + lane] = o;
    }
    __syncthreads();

    // phase C: GEMM, raw store
    int tx = tid & 31;
    int ty = tid >> 5;
    float4 accg[4];
#pragma unroll
    for (int i = 0; i < 4; ++i) accg[i] = make_float4(0.f, 0.f, 0.f, 0.f);

    for (int k4 = 0; k4 < 32; ++k4) {
        float4 w0 = Wl[(k4 * 4 + 0) * 32 + tx];
        float4 w1 = Wl[(k4 * 4 + 1) * 32 + tx];
        float4 w2 = Wl[(k4 * 4 + 2) * 32 + tx];
        float4 w3 = Wl[(k4 * 4 + 3) * 32 + tx];
#pragma unroll
        for (int i = 0; i < 4; ++i) {
            float4 xv = Xl[(ty * 4 + i) * 32 + k4];
            accg[i] = f4fma(xv.x, w0, accg[i]);
            accg[i] = f4fma(xv.y, w1, accg[i]);
            accg[i] = f4fma(xv.z, w2, accg[i]);
            accg[i] = f4fma(xv.w, w3, accg[i]);
        }
    }

    float4* G4 = (float4*)G2;
#pragma unroll
    for (int i = 0; i < 4; ++i) {
        int r = rbase + ty * 4 + i;
        G4[r * 32 + tx] = accg[i];
    }
}

// ---------------- F3: per-node agg(G2) + relu(dv*Y2+b2) + dots -> a, c ----------------
__global__ __launch_bounds__(256) void agg_head(const float* __restrict__ G2,
                                                const int* __restrict__ cnt,
                                                const int* __restrict__ bucket,
                                                const float* __restrict__ b2,
                                                const float* __restrict__ u,
                                                const float* __restrict__ v,
                                                const float* __restrict__ beta,
                                                float* __restrict__ a,
                                                float* __restrict__ c) {
    int node = blockIdx.x * 4 + (threadIdx.x >> 6);
    int lane = threadIdx.x & 63;
    const float2* G22 = (const float2*)G2;

    int deg = cnt[node];
    float dv = rsqrtf((float)(deg + 1));
    int i0 = bucket[(node << 7) + lane];
    int i1 = bucket[(node << 7) + 64 + lane];

    float2 p0 = G22[node * 64 + lane];  // self
    float2 p1 = {0.f, 0.f}, p2 = {0.f, 0.f}, p3 = {0.f, 0.f};

    int d4 = deg & ~3;
    for (int e = 0; e < d4; e += 4) {
        int s0 = __shfl((e + 0) >= 64 ? i1 : i0, (e + 0) & 63);
        int s1 = __shfl((e + 1) >= 64 ? i1 : i0, (e + 1) & 63);
        int s2 = __shfl((e + 2) >= 64 ? i1 : i0, (e + 2) & 63);
        int s3 = __shfl((e + 3) >= 64 ? i1 : i0, (e + 3) & 63);
        float2 t0 = G22[s0 * 64 + lane];
        float2 t1 = G22[s1 * 64 + lane];
        float2 t2 = G22[s2 * 64 + lane];
        float2 t3 = G22[s3 * 64 + lane];
        p0.x += t0.x; p0.y += t0.y;
        p1.x += t1.x; p1.y += t1.y;
        p2.x += t2.x; p2.y += t2.y;
        p3.x += t3.x; p3.y += t3.y;
    }
    for (int e = d4; e < deg; ++e) {
        int s = __shfl(e >= 64 ? i1 : i0, e & 63);
        float2 t = G22[s * 64 + lane];
        p0.x += t.x; p0.y += t.y;
    }
    float yx = (p0.x + p1.x) + (p2.x + p3.x);
    float yy = (p0.y + p1.y) + (p2.y + p3.y);

    const float2* B2 = (const float2*)b2;
    float2 bb = B2[lane];
    float h0 = fmaxf(fmaf(yx, dv, bb.x), 0.f);
    float h1 = fmaxf(fmaf(yy, dv, bb.y), 0.f);

    float2 uu = ((const float2*)u)[lane];
    float2 vv = ((const float2*)v)[lane];
    float pa = h0 * uu.x + h1 * uu.y;
    float pc = h0 * vv.x + h1 * vv.y;
#pragma unroll
    for (int off = 32; off >= 1; off >>= 1) {
        pa += __shfl_xor(pa, off);
        pc += __shfl_xor(pc, off);
    }
    if (lane == 0) {
        a[node] = pa + beta[0];
        c[node] = pc + beta[1];
    }
}

// ---------------- out[i][j] = a[i] + c[j] ----------------
__global__ __launch_bounds__(256) void out_kernel(const float* __restrict__ a,
                                                  const float* __restrict__ c,
                                                  f32x4* __restrict__ out) {
    const f32x4* c4 = (const f32x4*)c;
    size_t base = (size_t)blockIdx.x * 1024 + threadIdx.x;
#pragma unroll
    for (int q = 0; q < 4; ++q) {
        size_t idx = base + q * 256;
        int i = (int)(idx >> 11);
        int j4 = (int)(idx & 2047);
        f32x4 r = c4[j4] + a[i];
        __builtin_nontemporal_store(r, out + idx);
    }
}

extern "C" void kernel_launch(void* const* d_in, const int* in_sizes, int n_in,
                              void* d_out, int out_size, void* d_ws, size_t ws_size,
                              hipStream_t stream) {
    const float* x    = (const float*)d_in[0];
    const int*   ei   = (const int*)d_in[1];
    const float* W1   = (const float*)d_in[2];
    const float* b1   = (const float*)d_in[3];
    const float* W2   = (const float*)d_in[4];
    const float* b2   = (const float*)d_in[5];
    const float* Wout = (const float*)d_in[6];
    const float* bout = (const float*)d_in[7];
    const float* We   = (const float*)d_in[8];
    const float* bedge= (const float*)d_in[9];
    const int* src = ei;
    const int* dst = ei + NE;

    // workspace
    int* cnt     = (int*)d_ws;                    // 8192
    int* bucket  = cnt + NN;                      // 8192*128
    float* u     = (float*)(bucket + NN * BCAP);  // 128
    float* v     = u + DIM;                       // 128
    float* beta  = v + DIM;                       // 2 (pad 16)
    float* g1    = beta + 16;                     // 8192*128
    float* g2    = g1 + NN * DIM;                 // 8192*128
    float* av    = g2 + NN * DIM;                 // 8192
    float* cv    = av + NN;                       // 8192

    float* out = (float*)d_out;

    init_kernel<<<33, 256, 0, stream>>>(Wout, bout, We, bedge, cnt, u, v, beta);
    scatter_kernel<<<NE / 256, 256, 0, stream>>>(src, dst, cnt, bucket);
    gemm_pre<<<NN / 32, 256, 0, stream>>>(x, W1, cnt, g1);
    agg_gemm<<<NN / 32, 256, 0, stream>>>(g1, cnt, bucket, b1, W2, g2);
    agg_head<<<NN / 4, 256, 0, stream>>>(g2, cnt, bucket, b2, u, v, beta, av, cv);
    out_kernel<<<(NN * NN / 4) / 1024, 256, 0, stream>>>(av, cv, (f32x4*)out);
}

// Round 7
// 112.760 us; speedup vs baseline: 1.0744x; 1.0744x over previous
//
#include <hip/hip_runtime.h>

#define NN 8192      // nodes
#define NE 262144    // edges
#define DIM 128
#define BCAP 128     // bucket capacity (deg ~ Poisson(32); P(deg>128) ~ 0)

typedef float f32x4 __attribute__((ext_vector_type(4)));
typedef float f32x2 __attribute__((ext_vector_type(2)));

__device__ __forceinline__ float4 f4fma(float s, float4 w, float4 acc) {
    acc.x = fmaf(s, w.x, acc.x);
    acc.y = fmaf(s, w.y, acc.y);
    acc.z = fmaf(s, w.z, acc.z);
    acc.w = fmaf(s, w.w, acc.w);
    return acc;
}
__device__ __forceinline__ float f4dot(float4 a, float4 b) {
    return fmaf(a.x, b.x, fmaf(a.y, b.y, fmaf(a.z, b.z, a.w * b.w)));
}

// ---------------- K1: zero cnt ----------------
__global__ __launch_bounds__(256) void zero_kernel(int* __restrict__ cnt) {
    cnt[blockIdx.x * 256 + threadIdx.x] = 0;
}

// ---------------- K2: scatter edges into buckets (blocks 0..1023); uv/beta (block 1024) ----------------
__global__ __launch_bounds__(256) void scatter_uv(const int* __restrict__ src,
                                                  const int* __restrict__ dst,
                                                  int* __restrict__ cnt,
                                                  int* __restrict__ bucket,
                                                  const float* __restrict__ Wout,
                                                  const float* __restrict__ bout,
                                                  const float* __restrict__ we,
                                                  const float* __restrict__ bedge,
                                                  float* __restrict__ u,
                                                  float* __restrict__ v,
                                                  float* __restrict__ beta) {
    int k = threadIdx.x;
    if (blockIdx.x < 1024) {
        int e = blockIdx.x * 256 + k;
        int d = dst[e];
        int p = atomicAdd(&cnt[d], 1);
        if (p < BCAP) bucket[(d << 7) + p] = src[e];
        return;
    }
    // block 1024: u[k] = Wout[k,:] . we[:128], v[k] = Wout[k,:] . we[128:]
    if (k < DIM) {
        const float4* W4 = (const float4*)(Wout + (k << 7));
        const float4* we4 = (const float4*)we;
        float su = 0.f, sv = 0.f;
#pragma unroll
        for (int j = 0; j < 32; ++j) {
            float4 w = W4[j];
            su += f4dot(w, we4[j]);
            sv += f4dot(w, we4[32 + j]);
        }
        u[k] = su;
        v[k] = sv;
    }
    __shared__ float red[256];
    red[k] = (k < DIM) ? bout[k] * we[k] : 0.f;
    __syncthreads();
    for (int off = 128; off >= 1; off >>= 1) {
        if (k < off) red[k] += red[k + off];
        __syncthreads();
    }
    float b0 = red[0];
    __syncthreads();
    red[k] = (k < DIM) ? bout[k] * we[DIM + k] : 0.f;
    __syncthreads();
    for (int off = 128; off >= 1; off >>= 1) {
        if (k < off) red[k] += red[k + off];
        __syncthreads();
    }
    if (k == 0) {
        beta[0] = b0 + bedge[0];
        beta[1] = red[0];
    }
}

// ---------------- F1: G1[r] = (x @ W1)[r] * dinv[r], NT store ----------------
__global__ __launch_bounds__(256) void gemm_pre(const float* __restrict__ X,
                                                const float* __restrict__ W,
                                                const int* __restrict__ cnt,
                                                f32x4* __restrict__ G) {
    __shared__ float4 Wl[128 * 32];
    __shared__ float4 Xl[32 * 32];
    int tid = threadIdx.x;
    int rbase = blockIdx.x * 32;

    const float4* W4 = (const float4*)W;
#pragma unroll
    for (int i = 0; i < 16; ++i) Wl[i * 256 + tid] = W4[i * 256 + tid];
    const float4* X4 = (const float4*)(X + rbase * DIM);
#pragma unroll
    for (int i = 0; i < 4; ++i) Xl[i * 256 + tid] = X4[i * 256 + tid];
    __syncthreads();

    int tx = tid & 31;
    int ty = tid >> 5;
    float4 acc[4];
#pragma unroll
    for (int i = 0; i < 4; ++i) acc[i] = make_float4(0.f, 0.f, 0.f, 0.f);

    for (int k4 = 0; k4 < 32; ++k4) {
        float4 w0 = Wl[(k4 * 4 + 0) * 32 + tx];
        float4 w1 = Wl[(k4 * 4 + 1) * 32 + tx];
        float4 w2 = Wl[(k4 * 4 + 2) * 32 + tx];
        float4 w3 = Wl[(k4 * 4 + 3) * 32 + tx];
#pragma unroll
        for (int i = 0; i < 4; ++i) {
            float4 xv = Xl[(ty * 4 + i) * 32 + k4];
            acc[i] = f4fma(xv.x, w0, acc[i]);
            acc[i] = f4fma(xv.y, w1, acc[i]);
            acc[i] = f4fma(xv.z, w2, acc[i]);
            acc[i] = f4fma(xv.w, w3, acc[i]);
        }
    }

#pragma unroll
    for (int i = 0; i < 4; ++i) {
        int r = rbase + ty * 4 + i;
        float dv = rsqrtf((float)(cnt[r] + 1));
        f32x4 o = {acc[i].x * dv, acc[i].y * dv, acc[i].z * dv, acc[i].w * dv};
        __builtin_nontemporal_store(o, G + r * 32 + tx);
    }
}

// ---------------- F2: gather(G1) + S2 = dv*relu(dv*y + b1), NT out ----------------
// one wave per node; bucket loads NT so the 4MiB G1 table stays L2-resident.
__global__ __launch_bounds__(256) void gather_scale(const float* __restrict__ G1,
                                                    const int* __restrict__ cnt,
                                                    const int* __restrict__ bucket,
                                                    const float* __restrict__ b1,
                                                    f32x2* __restrict__ S2) {
    int node = blockIdx.x * 4 + (threadIdx.x >> 6);
    int lane = threadIdx.x & 63;
    const float2* G12 = (const float2*)G1;

    int deg = cnt[node];
    float dv = rsqrtf((float)(deg + 1));
    int i0 = __builtin_nontemporal_load(bucket + (node << 7) + lane);
    int i1 = __builtin_nontemporal_load(bucket + (node << 7) + 64 + lane);

    float2 p0 = G12[node * 64 + lane];  // self
    float2 p1 = {0.f, 0.f}, p2 = {0.f, 0.f}, p3 = {0.f, 0.f};

    int d4 = deg & ~3;
    for (int e = 0; e < d4; e += 4) {
        int s0 = __shfl((e + 0) >= 64 ? i1 : i0, (e + 0) & 63);
        int s1 = __shfl((e + 1) >= 64 ? i1 : i0, (e + 1) & 63);
        int s2 = __shfl((e + 2) >= 64 ? i1 : i0, (e + 2) & 63);
        int s3 = __shfl((e + 3) >= 64 ? i1 : i0, (e + 3) & 63);
        float2 t0 = G12[s0 * 64 + lane];
        float2 t1 = G12[s1 * 64 + lane];
        float2 t2 = G12[s2 * 64 + lane];
        float2 t3 = G12[s3 * 64 + lane];
        p0.x += t0.x; p0.y += t0.y;
        p1.x += t1.x; p1.y += t1.y;
        p2.x += t2.x; p2.y += t2.y;
        p3.x += t3.x; p3.y += t3.y;
    }
    for (int e = d4; e < deg; ++e) {
        int s = __shfl(e >= 64 ? i1 : i0, e & 63);
        float2 t = G12[s * 64 + lane];
        p0.x += t.x; p0.y += t.y;
    }
    float yx = (p0.x + p1.x) + (p2.x + p3.x);
    float yy = (p0.y + p1.y) + (p2.y + p3.y);

    const float2* B2 = (const float2*)b1;
    float2 bb = B2[lane];
    f32x2 o;
    o.x = fmaxf(fmaf(yx, dv, bb.x), 0.f) * dv;
    o.y = fmaxf(fmaf(yy, dv, bb.y), 0.f) * dv;
    __builtin_nontemporal_store(o, S2 + node * 64 + lane);
}

// ---------------- F3: G2 = S2 @ W2 (raw), NT store ----------------
__global__ __launch_bounds__(256) void gemm_mid(const float* __restrict__ X,
                                                const float* __restrict__ W,
                                                f32x4* __restrict__ G) {
    __shared__ float4 Wl[128 * 32];
    __shared__ float4 Xl[32 * 32];
    int tid = threadIdx.x;
    int rbase = blockIdx.x * 32;

    const float4* W4 = (const float4*)W;
#pragma unroll
    for (int i = 0; i < 16; ++i) Wl[i * 256 + tid] = W4[i * 256 + tid];
    const float4* X4 = (const float4*)(X + rbase * DIM);
#pragma unroll
    for (int i = 0; i < 4; ++i) Xl[i * 256 + tid] = X4[i * 256 + tid];
    __syncthreads();

    int tx = tid & 31;
    int ty = tid >> 5;
    float4 acc[4];
#pragma unroll
    for (int i = 0; i < 4; ++i) acc[i] = make_float4(0.f, 0.f, 0.f, 0.f);

    for (int k4 = 0; k4 < 32; ++k4) {
        float4 w0 = Wl[(k4 * 4 + 0) * 32 + tx];
        float4 w1 = Wl[(k4 * 4 + 1) * 32 + tx];
        float4 w2 = Wl[(k4 * 4 + 2) * 32 + tx];
        float4 w3 = Wl[(k4 * 4 + 3) * 32 + tx];
#pragma unroll
        for (int i = 0; i < 4; ++i) {
            float4 xv = Xl[(ty * 4 + i) * 32 + k4];
            acc[i] = f4fma(xv.x, w0, acc[i]);
            acc[i] = f4fma(xv.y, w1, acc[i]);
            acc[i] = f4fma(xv.z, w2, acc[i]);
            acc[i] = f4fma(xv.w, w3, acc[i]);
        }
    }

#pragma unroll
    for (int i = 0; i < 4; ++i) {
        int r = rbase + ty * 4 + i;
        f32x4 o = {acc[i].x, acc[i].y, acc[i].z, acc[i].w};
        __builtin_nontemporal_store(o, G + r * 32 + tx);
    }
}

// ---------------- F4: gather(G2) + head -> a, c ----------------
__global__ __launch_bounds__(256) void agg_head(const float* __restrict__ G2,
                                                const int* __restrict__ cnt,
                                                const int* __restrict__ bucket,
                                                const float* __restrict__ b2,
                                                const float* __restrict__ u,
                                                const float* __restrict__ v,
                                                const float* __restrict__ beta,
                                                float* __restrict__ a,
                                                float* __restrict__ c) {
    int node = blockIdx.x * 4 + (threadIdx.x >> 6);
    int lane = threadIdx.x & 63;
    const float2* G22 = (const float2*)G2;

    int deg = cnt[node];
    float dv = rsqrtf((float)(deg + 1));
    int i0 = __builtin_nontemporal_load(bucket + (node << 7) + lane);
    int i1 = __builtin_nontemporal_load(bucket + (node << 7) + 64 + lane);

    float2 p0 = G22[node * 64 + lane];  // self
    float2 p1 = {0.f, 0.f}, p2 = {0.f, 0.f}, p3 = {0.f, 0.f};

    int d4 = deg & ~3;
    for (int e = 0; e < d4; e += 4) {
        int s0 = __shfl((e + 0) >= 64 ? i1 : i0, (e + 0) & 63);
        int s1 = __shfl((e + 1) >= 64 ? i1 : i0, (e + 1) & 63);
        int s2 = __shfl((e + 2) >= 64 ? i1 : i0, (e + 2) & 63);
        int s3 = __shfl((e + 3) >= 64 ? i1 : i0, (e + 3) & 63);
        float2 t0 = G22[s0 * 64 + lane];
        float2 t1 = G22[s1 * 64 + lane];
        float2 t2 = G22[s2 * 64 + lane];
        float2 t3 = G22[s3 * 64 + lane];
        p0.x += t0.x; p0.y += t0.y;
        p1.x += t1.x; p1.y += t1.y;
        p2.x += t2.x; p2.y += t2.y;
        p3.x += t3.x; p3.y += t3.y;
    }
    for (int e = d4; e < deg; ++e) {
        int s = __shfl(e >= 64 ? i1 : i0, e & 63);
        float2 t = G22[s * 64 + lane];
        p0.x += t.x; p0.y += t.y;
    }
    float yx = (p0.x + p1.x) + (p2.x + p3.x);
    float yy = (p0.y + p1.y) + (p2.y + p3.y);

    const float2* B2 = (const float2*)b2;
    float2 bb = B2[lane];
    float h0 = fmaxf(fmaf(yx, dv, bb.x), 0.f);
    float h1 = fmaxf(fmaf(yy, dv, bb.y), 0.f);

    float2 uu = ((const float2*)u)[lane];
    float2 vv = ((const float2*)v)[lane];
    float pa = h0 * uu.x + h1 * uu.y;
    float pc = h0 * vv.x + h1 * vv.y;
#pragma unroll
    for (int off = 32; off >= 1; off >>= 1) {
        pa += __shfl_xor(pa, off);
        pc += __shfl_xor(pc, off);
    }
    if (lane == 0) {
        a[node] = pa + beta[0];
        c[node] = pc + beta[1];
    }
}

// ---------------- out[i][j] = a[i] + c[j] ----------------
__global__ __launch_bounds__(256) void out_kernel(const float* __restrict__ a,
                                                  const float* __restrict__ c,
                                                  f32x4* __restrict__ out) {
    const f32x4* c4 = (const f32x4*)c;
    size_t base = (size_t)blockIdx.x * 1024 + threadIdx.x;
#pragma unroll
    for (int q = 0; q < 4; ++q) {
        size_t idx = base + q * 256;
        int i = (int)(idx >> 11);
        int j4 = (int)(idx & 2047);
        f32x4 r = c4[j4] + a[i];
        __builtin_nontemporal_store(r, out + idx);
    }
}

extern "C" void kernel_launch(void* const* d_in, const int* in_sizes, int n_in,
                              void* d_out, int out_size, void* d_ws, size_t ws_size,
                              hipStream_t stream) {
    const float* x    = (const float*)d_in[0];
    const int*   ei   = (const int*)d_in[1];
    const float* W1   = (const float*)d_in[2];
    const float* b1   = (const float*)d_in[3];
    const float* W2   = (const float*)d_in[4];
    const float* b2   = (const float*)d_in[5];
    const float* Wout = (const float*)d_in[6];
    const float* bout = (const float*)d_in[7];
    const float* We   = (const float*)d_in[8];
    const float* bedge= (const float*)d_in[9];
    const int* src = ei;
    const int* dst = ei + NE;

    // workspace
    int* cnt     = (int*)d_ws;                    // 8192
    int* bucket  = cnt + NN;                      // 8192*128
    float* u     = (float*)(bucket + NN * BCAP);  // 128
    float* v     = u + DIM;                       // 128
    float* beta  = v + DIM;                       // 2 (pad 16)
    float* g1    = beta + 16;                     // 8192*128
    float* s2    = g1 + NN * DIM;                 // 8192*128
    float* g2    = s2 + NN * DIM;                 // 8192*128
    float* av    = g2 + NN * DIM;                 // 8192
    float* cv    = av + NN;                       // 8192

    float* out = (float*)d_out;

    zero_kernel<<<32, 256, 0, stream>>>(cnt);
    scatter_uv<<<1025, 256, 0, stream>>>(src, dst, cnt, bucket,
                                         Wout, bout, We, bedge, u, v, beta);
    gemm_pre<<<NN / 32, 256, 0, stream>>>(x, W1, cnt, (f32x4*)g1);
    gather_scale<<<NN / 4, 256, 0, stream>>>(g1, cnt, bucket, b1, (f32x2*)s2);
    gemm_mid<<<NN / 32, 256, 0, stream>>>(s2, W2, (f32x4*)g2);
    agg_head<<<NN / 4, 256, 0, stream>>>(g2, cnt, bucket, b2, u, v, beta, av, cv);
    out_kernel<<<(NN * NN / 4) / 1024, 256, 0, stream>>>(av, cv, (f32x4*)out);
}

// Round 8
// 110.501 us; speedup vs baseline: 1.0964x; 1.0204x over previous
//
#include <hip/hip_runtime.h>

#define NN 8192      // nodes
#define NE 262144    // edges
#define DIM 128
#define BCAP 128     // bucket capacity (deg ~ Poisson(32); P(deg>128) ~ 0)

typedef float f32x4 __attribute__((ext_vector_type(4)));
typedef float f32x2 __attribute__((ext_vector_type(2)));

__device__ __forceinline__ float4 f4fma(float s, float4 w, float4 acc) {
    acc.x = fmaf(s, w.x, acc.x);
    acc.y = fmaf(s, w.y, acc.y);
    acc.z = fmaf(s, w.z, acc.z);
    acc.w = fmaf(s, w.w, acc.w);
    return acc;
}
__device__ __forceinline__ float f4dot(float4 a, float4 b) {
    return fmaf(a.x, b.x, fmaf(a.y, b.y, fmaf(a.z, b.z, a.w * b.w)));
}

// ---------------- K1: zero cnt ----------------
__global__ __launch_bounds__(256) void zero_kernel(int* __restrict__ cnt) {
    cnt[blockIdx.x * 256 + threadIdx.x] = 0;
}

// ---------------- K2: scatter edges into buckets (blocks 0..1023); uv/beta (block 1024) ----------------
__global__ __launch_bounds__(256) void scatter_uv(const int* __restrict__ src,
                                                  const int* __restrict__ dst,
                                                  int* __restrict__ cnt,
                                                  int* __restrict__ bucket,
                                                  const float* __restrict__ Wout,
                                                  const float* __restrict__ bout,
                                                  const float* __restrict__ we,
                                                  const float* __restrict__ bedge,
                                                  float* __restrict__ u,
                                                  float* __restrict__ v,
                                                  float* __restrict__ beta) {
    int k = threadIdx.x;
    if (blockIdx.x < 1024) {
        int e = blockIdx.x * 256 + k;
        int d = dst[e];
        int p = atomicAdd(&cnt[d], 1);
        if (p < BCAP) bucket[(d << 7) + p] = src[e];
        return;
    }
    // block 1024: u[k] = Wout[k,:] . we[:128], v[k] = Wout[k,:] . we[128:]
    if (k < DIM) {
        const float4* W4 = (const float4*)(Wout + (k << 7));
        const float4* we4 = (const float4*)we;
        float su = 0.f, sv = 0.f;
#pragma unroll
        for (int j = 0; j < 32; ++j) {
            float4 w = W4[j];
            su += f4dot(w, we4[j]);
            sv += f4dot(w, we4[32 + j]);
        }
        u[k] = su;
        v[k] = sv;
    }
    __shared__ float red[256];
    red[k] = (k < DIM) ? bout[k] * we[k] : 0.f;
    __syncthreads();
    for (int off = 128; off >= 1; off >>= 1) {
        if (k < off) red[k] += red[k + off];
        __syncthreads();
    }
    float b0 = red[0];
    __syncthreads();
    red[k] = (k < DIM) ? bout[k] * we[DIM + k] : 0.f;
    __syncthreads();
    for (int off = 128; off >= 1; off >>= 1) {
        if (k < off) red[k] += red[k + off];
        __syncthreads();
    }
    if (k == 0) {
        beta[0] = b0 + bedge[0];
        beta[1] = red[0];
    }
}

// ---------------- F1: G1[r] = (x @ W1)[r] * dinv[r], NT store ----------------
__global__ __launch_bounds__(256) void gemm_pre(const float* __restrict__ X,
                                                const float* __restrict__ W,
                                                const int* __restrict__ cnt,
                                                f32x4* __restrict__ G) {
    __shared__ float4 Wl[128 * 32];
    __shared__ float4 Xl[32 * 32];
    int tid = threadIdx.x;
    int rbase = blockIdx.x * 32;

    const float4* W4 = (const float4*)W;
#pragma unroll
    for (int i = 0; i < 16; ++i) Wl[i * 256 + tid] = W4[i * 256 + tid];
    const float4* X4 = (const float4*)(X + rbase * DIM);
#pragma unroll
    for (int i = 0; i < 4; ++i) Xl[i * 256 + tid] = X4[i * 256 + tid];
    __syncthreads();

    int tx = tid & 31;
    int ty = tid >> 5;
    float4 acc[4];
#pragma unroll
    for (int i = 0; i < 4; ++i) acc[i] = make_float4(0.f, 0.f, 0.f, 0.f);

    for (int k4 = 0; k4 < 32; ++k4) {
        float4 w0 = Wl[(k4 * 4 + 0) * 32 + tx];
        float4 w1 = Wl[(k4 * 4 + 1) * 32 + tx];
        float4 w2 = Wl[(k4 * 4 + 2) * 32 + tx];
        float4 w3 = Wl[(k4 * 4 + 3) * 32 + tx];
#pragma unroll
        for (int i = 0; i < 4; ++i) {
            float4 xv = Xl[(ty * 4 + i) * 32 + k4];
            acc[i] = f4fma(xv.x, w0, acc[i]);
            acc[i] = f4fma(xv.y, w1, acc[i]);
            acc[i] = f4fma(xv.z, w2, acc[i]);
            acc[i] = f4fma(xv.w, w3, acc[i]);
        }
    }

#pragma unroll
    for (int i = 0; i < 4; ++i) {
        int r = rbase + ty * 4 + i;
        float dv = rsqrtf((float)(cnt[r] + 1));
        f32x4 o = {acc[i].x * dv, acc[i].y * dv, acc[i].z * dv, acc[i].w * dv};
        __builtin_nontemporal_store(o, G + r * 32 + tx);
    }
}

// ---------------- F2: gather(G1) + S2 = dv*relu(dv*y + b1), NT out ----------------
__global__ __launch_bounds__(256) void gather_scale(const float* __restrict__ G1,
                                                    const int* __restrict__ cnt,
                                                    const int* __restrict__ bucket,
                                                    const float* __restrict__ b1,
                                                    f32x2* __restrict__ S2) {
    int node = blockIdx.x * 4 + (threadIdx.x >> 6);
    int lane = threadIdx.x & 63;
    const float2* G12 = (const float2*)G1;

    int deg = cnt[node];
    float dv = rsqrtf((float)(deg + 1));
    int i0 = __builtin_nontemporal_load(bucket + (node << 7) + lane);
    int i1 = __builtin_nontemporal_load(bucket + (node << 7) + 64 + lane);

    float2 p0 = G12[node * 64 + lane];  // self
    float2 p1 = {0.f, 0.f}, p2 = {0.f, 0.f}, p3 = {0.f, 0.f};

    int d4 = deg & ~3;
    for (int e = 0; e < d4; e += 4) {
        int s0 = __shfl((e + 0) >= 64 ? i1 : i0, (e + 0) & 63);
        int s1 = __shfl((e + 1) >= 64 ? i1 : i0, (e + 1) & 63);
        int s2 = __shfl((e + 2) >= 64 ? i1 : i0, (e + 2) & 63);
        int s3 = __shfl((e + 3) >= 64 ? i1 : i0, (e + 3) & 63);
        float2 t0 = G12[s0 * 64 + lane];
        float2 t1 = G12[s1 * 64 + lane];
        float2 t2 = G12[s2 * 64 + lane];
        float2 t3 = G12[s3 * 64 + lane];
        p0.x += t0.x; p0.y += t0.y;
        p1.x += t1.x; p1.y += t1.y;
        p2.x += t2.x; p2.y += t2.y;
        p3.x += t3.x; p3.y += t3.y;
    }
    for (int e = d4; e < deg; ++e) {
        int s = __shfl(e >= 64 ? i1 : i0, e & 63);
        float2 t = G12[s * 64 + lane];
        p0.x += t.x; p0.y += t.y;
    }
    float yx = (p0.x + p1.x) + (p2.x + p3.x);
    float yy = (p0.y + p1.y) + (p2.y + p3.y);

    const float2* B2 = (const float2*)b1;
    float2 bb = B2[lane];
    f32x2 o;
    o.x = fmaxf(fmaf(yx, dv, bb.x), 0.f) * dv;
    o.y = fmaxf(fmaf(yy, dv, bb.y), 0.f) * dv;
    __builtin_nontemporal_store(o, S2 + node * 64 + lane);
}

// ---------------- F3: G2 = S2 @ W2 (raw), NT store ----------------
__global__ __launch_bounds__(256) void gemm_mid(const float* __restrict__ X,
                                                const float* __restrict__ W,
                                                f32x4* __restrict__ G) {
    __shared__ float4 Wl[128 * 32];
    __shared__ float4 Xl[32 * 32];
    int tid = threadIdx.x;
    int rbase = blockIdx.x * 32;

    const float4* W4 = (const float4*)W;
#pragma unroll
    for (int i = 0; i < 16; ++i) Wl[i * 256 + tid] = W4[i * 256 + tid];
    const float4* X4 = (const float4*)(X + rbase * DIM);
#pragma unroll
    for (int i = 0; i < 4; ++i) Xl[i * 256 + tid] = X4[i * 256 + tid];
    __syncthreads();

    int tx = tid & 31;
    int ty = tid >> 5;
    float4 acc[4];
#pragma unroll
    for (int i = 0; i < 4; ++i) acc[i] = make_float4(0.f, 0.f, 0.f, 0.f);

    for (int k4 = 0; k4 < 32; ++k4) {
        float4 w0 = Wl[(k4 * 4 + 0) * 32 + tx];
        float4 w1 = Wl[(k4 * 4 + 1) * 32 + tx];
        float4 w2 = Wl[(k4 * 4 + 2) * 32 + tx];
        float4 w3 = Wl[(k4 * 4 + 3) * 32 + tx];
#pragma unroll
        for (int i = 0; i < 4; ++i) {
            float4 xv = Xl[(ty * 4 + i) * 32 + k4];
            acc[i] = f4fma(xv.x, w0, acc[i]);
            acc[i] = f4fma(xv.y, w1, acc[i]);
            acc[i] = f4fma(xv.z, w2, acc[i]);
            acc[i] = f4fma(xv.w, w3, acc[i]);
        }
    }

#pragma unroll
    for (int i = 0; i < 4; ++i) {
        int r = rbase + ty * 4 + i;
        f32x4 o = {acc[i].x, acc[i].y, acc[i].z, acc[i].w};
        __builtin_nontemporal_store(o, G + r * 32 + tx);
    }
}

// ---------------- F4: gather(G2) + head -> a, c ----------------
__global__ __launch_bounds__(256) void agg_head(const float* __restrict__ G2,
                                                const int* __restrict__ cnt,
                                                const int* __restrict__ bucket,
                                                const float* __restrict__ b2,
                                                const float* __restrict__ u,
                                                const float* __restrict__ v,
                                                const float* __restrict__ beta,
                                                float* __restrict__ a,
                                                float* __restrict__ c) {
    int node = blockIdx.x * 4 + (threadIdx.x >> 6);
    int lane = threadIdx.x & 63;
    const float2* G22 = (const float2*)G2;

    int deg = cnt[node];
    float dv = rsqrtf((float)(deg + 1));
    int i0 = __builtin_nontemporal_load(bucket + (node << 7) + lane);
    int i1 = __builtin_nontemporal_load(bucket + (node << 7) + 64 + lane);

    float2 p0 = G22[node * 64 + lane];  // self
    float2 p1 = {0.f, 0.f}, p2 = {0.f, 0.f}, p3 = {0.f, 0.f};

    int d4 = deg & ~3;
    for (int e = 0; e < d4; e += 4) {
        int s0 = __shfl((e + 0) >= 64 ? i1 : i0, (e + 0) & 63);
        int s1 = __shfl((e + 1) >= 64 ? i1 : i0, (e + 1) & 63);
        int s2 = __shfl((e + 2) >= 64 ? i1 : i0, (e + 2) & 63);
        int s3 = __shfl((e + 3) >= 64 ? i1 : i0, (e + 3) & 63);
        float2 t0 = G22[s0 * 64 + lane];
        float2 t1 = G22[s1 * 64 + lane];
        float2 t2 = G22[s2 * 64 + lane];
        float2 t3 = G22[s3 * 64 + lane];
        p0.x += t0.x; p0.y += t0.y;
        p1.x += t1.x; p1.y += t1.y;
        p2.x += t2.x; p2.y += t2.y;
        p3.x += t3.x; p3.y += t3.y;
    }
    for (int e = d4; e < deg; ++e) {
        int s = __shfl(e >= 64 ? i1 : i0, e & 63);
        float2 t = G22[s * 64 + lane];
        p0.x += t.x; p0.y += t.y;
    }
    float yx = (p0.x + p1.x) + (p2.x + p3.x);
    float yy = (p0.y + p1.y) + (p2.y + p3.y);

    const float2* B2 = (const float2*)b2;
    float2 bb = B2[lane];
    float h0 = fmaxf(fmaf(yx, dv, bb.x), 0.f);
    float h1 = fmaxf(fmaf(yy, dv, bb.y), 0.f);

    float2 uu = ((const float2*)u)[lane];
    float2 vv = ((const float2*)v)[lane];
    float pa = h0 * uu.x + h1 * uu.y;
    float pc = h0 * vv.x + h1 * vv.y;
#pragma unroll
    for (int off = 32; off >= 1; off >>= 1) {
        pa += __shfl_xor(pa, off);
        pc += __shfl_xor(pc, off);
    }
    if (lane == 0) {
        a[node] = pa + beta[0];
        c[node] = pc + beta[1];
    }
}

// ---------------- out[i][j] = a[i] + c[j] ----------------
// SINGLE-VARIABLE CHANGE vs R7: plain stores (fillBuffer-proven path), no NT flag.
__global__ __launch_bounds__(256) void out_kernel(const float* __restrict__ a,
                                                  const float* __restrict__ c,
                                                  f32x4* __restrict__ out) {
    const f32x4* c4 = (const f32x4*)c;
    size_t base = (size_t)blockIdx.x * 1024 + threadIdx.x;
#pragma unroll
    for (int q = 0; q < 4; ++q) {
        size_t idx = base + q * 256;
        int i = (int)(idx >> 11);
        int j4 = (int)(idx & 2047);
        f32x4 r = c4[j4] + a[i];
        out[idx] = r;
    }
}

extern "C" void kernel_launch(void* const* d_in, const int* in_sizes, int n_in,
                              void* d_out, int out_size, void* d_ws, size_t ws_size,
                              hipStream_t stream) {
    const float* x    = (const float*)d_in[0];
    const int*   ei   = (const int*)d_in[1];
    const float* W1   = (const float*)d_in[2];
    const float* b1   = (const float*)d_in[3];
    const float* W2   = (const float*)d_in[4];
    const float* b2   = (const float*)d_in[5];
    const float* Wout = (const float*)d_in[6];
    const float* bout = (const float*)d_in[7];
    const float* We   = (const float*)d_in[8];
    const float* bedge= (const float*)d_in[9];
    const int* src = ei;
    const int* dst = ei + NE;

    // workspace
    int* cnt     = (int*)d_ws;                    // 8192
    int* bucket  = cnt + NN;                      // 8192*128
    float* u     = (float*)(bucket + NN * BCAP);  // 128
    float* v     = u + DIM;                       // 128
    float* beta  = v + DIM;                       // 2 (pad 16)
    float* g1    = beta + 16;                     // 8192*128
    float* s2    = g1 + NN * DIM;                 // 8192*128
    float* g2    = s2 + NN * DIM;                 // 8192*128
    float* av    = g2 + NN * DIM;                 // 8192
    float* cv    = av + NN;                       // 8192

    float* out = (float*)d_out;

    zero_kernel<<<32, 256, 0, stream>>>(cnt);
    scatter_uv<<<1025, 256, 0, stream>>>(src, dst, cnt, bucket,
                                         Wout, bout, We, bedge, u, v, beta);
    gemm_pre<<<NN / 32, 256, 0, stream>>>(x, W1, cnt, (f32x4*)g1);
    gather_scale<<<NN / 4, 256, 0, stream>>>(g1, cnt, bucket, b1, (f32x2*)s2);
    gemm_mid<<<NN / 32, 256, 0, stream>>>(s2, W2, (f32x4*)g2);
    agg_head<<<NN / 4, 256, 0, stream>>>(g2, cnt, bucket, b2, u, v, beta, av, cv);
    out_kernel<<<(NN * NN / 4) / 1024, 256, 0, stream>>>(av, cv, (f32x4*)out);
}

// Round 9
// 109.998 us; speedup vs baseline: 1.1014x; 1.0046x over previous
//
#include <hip/hip_runtime.h>

#define NN 8192      // nodes
#define NE 262144    // edges
#define DIM 128
#define BCAP 128     // bucket capacity (deg ~ Poisson(32); P(deg>128) ~ 0)

typedef float f32x4 __attribute__((ext_vector_type(4)));
typedef float f32x2 __attribute__((ext_vector_type(2)));

__device__ __forceinline__ float4 f4fma(float s, float4 w, float4 acc) {
    acc.x = fmaf(s, w.x, acc.x);
    acc.y = fmaf(s, w.y, acc.y);
    acc.z = fmaf(s, w.z, acc.z);
    acc.w = fmaf(s, w.w, acc.w);
    return acc;
}
__device__ __forceinline__ float f4dot(float4 a, float4 b) {
    return fmaf(a.x, b.x, fmaf(a.y, b.y, fmaf(a.z, b.z, a.w * b.w)));
}

// ---------------- K1: zero cnt ----------------
__global__ __launch_bounds__(256) void zero_kernel(int* __restrict__ cnt) {
    cnt[blockIdx.x * 256 + threadIdx.x] = 0;
}

// ---------------- K2: fused [gemm_pre_raw (blk 0-255)] | [scatter (blk 256-1279)] | [uv (blk 1280)] ----------------
__global__ __launch_bounds__(256) void fused_pre(const float* __restrict__ X,
                                                 const float* __restrict__ W,
                                                 f32x4* __restrict__ G,
                                                 const int* __restrict__ src,
                                                 const int* __restrict__ dst,
                                                 int* __restrict__ cnt,
                                                 int* __restrict__ bucket,
                                                 const float* __restrict__ Wout,
                                                 const float* __restrict__ bout,
                                                 const float* __restrict__ we,
                                                 const float* __restrict__ bedge,
                                                 float* __restrict__ u,
                                                 float* __restrict__ v,
                                                 float* __restrict__ beta) {
    __shared__ float4 Wl[128 * 32];  // 64KB (gemm branch only)
    __shared__ float4 Xl[32 * 32];   // 16KB (gemm); overlaid as red[] by uv branch
    int tid = threadIdx.x;
    int bid = blockIdx.x;

    if (bid < 256) {
        // ---- raw GEMM: G1[r] = (x @ W1)[r] (dinv commuted into gather) ----
        int rbase = bid * 32;
        const float4* W4 = (const float4*)W;
#pragma unroll
        for (int i = 0; i < 16; ++i) Wl[i * 256 + tid] = W4[i * 256 + tid];
        const float4* X4 = (const float4*)(X + rbase * DIM);
#pragma unroll
        for (int i = 0; i < 4; ++i) Xl[i * 256 + tid] = X4[i * 256 + tid];
        __syncthreads();

        int tx = tid & 31;
        int ty = tid >> 5;
        float4 acc[4];
#pragma unroll
        for (int i = 0; i < 4; ++i) acc[i] = make_float4(0.f, 0.f, 0.f, 0.f);

        for (int k4 = 0; k4 < 32; ++k4) {
            float4 w0 = Wl[(k4 * 4 + 0) * 32 + tx];
            float4 w1 = Wl[(k4 * 4 + 1) * 32 + tx];
            float4 w2 = Wl[(k4 * 4 + 2) * 32 + tx];
            float4 w3 = Wl[(k4 * 4 + 3) * 32 + tx];
#pragma unroll
            for (int i = 0; i < 4; ++i) {
                float4 xv = Xl[(ty * 4 + i) * 32 + k4];
                acc[i] = f4fma(xv.x, w0, acc[i]);
                acc[i] = f4fma(xv.y, w1, acc[i]);
                acc[i] = f4fma(xv.z, w2, acc[i]);
                acc[i] = f4fma(xv.w, w3, acc[i]);
            }
        }
#pragma unroll
        for (int i = 0; i < 4; ++i) {
            int r = rbase + ty * 4 + i;
            f32x4 o = {acc[i].x, acc[i].y, acc[i].z, acc[i].w};
            __builtin_nontemporal_store(o, G + r * 32 + tx);
        }
        return;
    }
    if (bid < 1280) {
        // ---- scatter edges into buckets; cnt ends as indegree ----
        int e = (bid - 256) * 256 + tid;
        int d = dst[e];
        int p = atomicAdd(&cnt[d], 1);
        if (p < BCAP) bucket[(d << 7) + p] = src[e];
        return;
    }
    // ---- block 1280: u/v/beta ----
    float* red = (float*)Xl;
    int k = tid;
    if (k < DIM) {
        const float4* W4o = (const float4*)(Wout + (k << 7));
        const float4* we4 = (const float4*)we;
        float su = 0.f, sv = 0.f;
#pragma unroll
        for (int j = 0; j < 32; ++j) {
            float4 w = W4o[j];
            su += f4dot(w, we4[j]);
            sv += f4dot(w, we4[32 + j]);
        }
        u[k] = su;
        v[k] = sv;
    }
    red[k] = (k < DIM) ? bout[k] * we[k] : 0.f;
    __syncthreads();
    for (int off = 128; off >= 1; off >>= 1) {
        if (k < off) red[k] += red[k + off];
        __syncthreads();
    }
    float b0 = red[0];
    __syncthreads();
    red[k] = (k < DIM) ? bout[k] * we[DIM + k] : 0.f;
    __syncthreads();
    for (int off = 128; off >= 1; off >>= 1) {
        if (k < off) red[k] += red[k + off];
        __syncthreads();
    }
    if (k == 0) {
        beta[0] = b0 + bedge[0];
        beta[1] = red[0];
    }
}

// ---------------- F2: gather(G1raw, per-edge dinv) + S2 = dv*relu(dv*y + b1) ----------------
__global__ __launch_bounds__(256) void gather_scale(const float* __restrict__ G1,
                                                    const int* __restrict__ cnt,
                                                    const int* __restrict__ bucket,
                                                    const float* __restrict__ b1,
                                                    f32x2* __restrict__ S2) {
    int node = blockIdx.x * 4 + (threadIdx.x >> 6);
    int lane = threadIdx.x & 63;
    const float2* G12 = (const float2*)G1;

    int degree = cnt[node];
    float dv = rsqrtf((float)(degree + 1));
    int deg = min(degree, BCAP);
    int i0 = __builtin_nontemporal_load(bucket + (node << 7) + lane);
    int i1 = __builtin_nontemporal_load(bucket + (node << 7) + 64 + lane);

    float2 selfv = G12[node * 64 + lane];
    float ax = selfv.x * dv, ay = selfv.y * dv;   // self: src dinv = own dv
    float px[8], py[8];
#pragma unroll
    for (int k = 0; k < 8; ++k) { px[k] = 0.f; py[k] = 0.f; }

    int d8 = deg & ~7;
    for (int e = 0; e < d8; e += 8) {
        int s[8];
#pragma unroll
        for (int k = 0; k < 8; ++k) s[k] = __shfl((e + k) >= 64 ? i1 : i0, (e + k) & 63);
#pragma unroll
        for (int k = 0; k < 8; ++k) {
            int ck = cnt[s[k]];
            float2 t = G12[s[k] * 64 + lane];
            float w = rsqrtf((float)(ck + 1));
            px[k] = fmaf(t.x, w, px[k]);
            py[k] = fmaf(t.y, w, py[k]);
        }
    }
    for (int e = d8; e < deg; ++e) {
        int s = __shfl(e >= 64 ? i1 : i0, e & 63);
        int ck = cnt[s];
        float2 t = G12[s * 64 + lane];
        float w = rsqrtf((float)(ck + 1));
        ax = fmaf(t.x, w, ax);
        ay = fmaf(t.y, w, ay);
    }
    float yx = ax + ((px[0] + px[1]) + (px[2] + px[3])) + ((px[4] + px[5]) + (px[6] + px[7]));
    float yy = ay + ((py[0] + py[1]) + (py[2] + py[3])) + ((py[4] + py[5]) + (py[6] + py[7]));

    const float2* B2 = (const float2*)b1;
    float2 bb = B2[lane];
    f32x2 o;
    o.x = fmaxf(fmaf(yx, dv, bb.x), 0.f) * dv;
    o.y = fmaxf(fmaf(yy, dv, bb.y), 0.f) * dv;
    __builtin_nontemporal_store(o, S2 + node * 64 + lane);
}

// ---------------- F3: G2 = S2 @ W2 (raw), NT store ----------------
__global__ __launch_bounds__(256) void gemm_mid(const float* __restrict__ X,
                                                const float* __restrict__ W,
                                                f32x4* __restrict__ G) {
    __shared__ float4 Wl[128 * 32];
    __shared__ float4 Xl[32 * 32];
    int tid = threadIdx.x;
    int rbase = blockIdx.x * 32;

    const float4* W4 = (const float4*)W;
#pragma unroll
    for (int i = 0; i < 16; ++i) Wl[i * 256 + tid] = W4[i * 256 + tid];
    const float4* X4 = (const float4*)(X + rbase * DIM);
#pragma unroll
    for (int i = 0; i < 4; ++i) Xl[i * 256 + tid] = X4[i * 256 + tid];
    __syncthreads();

    int tx = tid & 31;
    int ty = tid >> 5;
    float4 acc[4];
#pragma unroll
    for (int i = 0; i < 4; ++i) acc[i] = make_float4(0.f, 0.f, 0.f, 0.f);

    for (int k4 = 0; k4 < 32; ++k4) {
        float4 w0 = Wl[(k4 * 4 + 0) * 32 + tx];
        float4 w1 = Wl[(k4 * 4 + 1) * 32 + tx];
        float4 w2 = Wl[(k4 * 4 + 2) * 32 + tx];
        float4 w3 = Wl[(k4 * 4 + 3) * 32 + tx];
#pragma unroll
        for (int i = 0; i < 4; ++i) {
            float4 xv = Xl[(ty * 4 + i) * 32 + k4];
            acc[i] = f4fma(xv.x, w0, acc[i]);
            acc[i] = f4fma(xv.y, w1, acc[i]);
            acc[i] = f4fma(xv.z, w2, acc[i]);
            acc[i] = f4fma(xv.w, w3, acc[i]);
        }
    }

#pragma unroll
    for (int i = 0; i < 4; ++i) {
        int r = rbase + ty * 4 + i;
        f32x4 o = {acc[i].x, acc[i].y, acc[i].z, acc[i].w};
        __builtin_nontemporal_store(o, G + r * 32 + tx);
    }
}

// ---------------- F4: gather(G2) + head -> a, c (ILP-8) ----------------
__global__ __launch_bounds__(256) void agg_head(const float* __restrict__ G2,
                                                const int* __restrict__ cnt,
                                                const int* __restrict__ bucket,
                                                const float* __restrict__ b2,
                                                const float* __restrict__ u,
                                                const float* __restrict__ v,
                                                const float* __restrict__ beta,
                                                float* __restrict__ a,
                                                float* __restrict__ c) {
    int node = blockIdx.x * 4 + (threadIdx.x >> 6);
    int lane = threadIdx.x & 63;
    const float2* G22 = (const float2*)G2;

    int degree = cnt[node];
    float dv = rsqrtf((float)(degree + 1));
    int deg = min(degree, BCAP);
    int i0 = __builtin_nontemporal_load(bucket + (node << 7) + lane);
    int i1 = __builtin_nontemporal_load(bucket + (node << 7) + 64 + lane);

    float2 selfv = G22[node * 64 + lane];
    float ax = selfv.x, ay = selfv.y;
    float px[8], py[8];
#pragma unroll
    for (int k = 0; k < 8; ++k) { px[k] = 0.f; py[k] = 0.f; }

    int d8 = deg & ~7;
    for (int e = 0; e < d8; e += 8) {
        int s[8];
#pragma unroll
        for (int k = 0; k < 8; ++k) s[k] = __shfl((e + k) >= 64 ? i1 : i0, (e + k) & 63);
#pragma unroll
        for (int k = 0; k < 8; ++k) {
            float2 t = G22[s[k] * 64 + lane];
            px[k] += t.x;
            py[k] += t.y;
        }
    }
    for (int e = d8; e < deg; ++e) {
        int s = __shfl(e >= 64 ? i1 : i0, e & 63);
        float2 t = G22[s * 64 + lane];
        ax += t.x;
        ay += t.y;
    }
    float yx = ax + ((px[0] + px[1]) + (px[2] + px[3])) + ((px[4] + px[5]) + (px[6] + px[7]));
    float yy = ay + ((py[0] + py[1]) + (py[2] + py[3])) + ((py[4] + py[5]) + (py[6] + py[7]));

    const float2* B2 = (const float2*)b2;
    float2 bb = B2[lane];
    float h0 = fmaxf(fmaf(yx, dv, bb.x), 0.f);
    float h1 = fmaxf(fmaf(yy, dv, bb.y), 0.f);

    float2 uu = ((const float2*)u)[lane];
    float2 vv = ((const float2*)v)[lane];
    float pa = h0 * uu.x + h1 * uu.y;
    float pc = h0 * vv.x + h1 * vv.y;
#pragma unroll
    for (int off = 32; off >= 1; off >>= 1) {
        pa += __shfl_xor(pa, off);
        pc += __shfl_xor(pc, off);
    }
    if (lane == 0) {
        a[node] = pa + beta[0];
        c[node] = pc + beta[1];
    }
}

// ---------------- out[i][j] = a[i] + c[j] (plain stores — R8-proven) ----------------
__global__ __launch_bounds__(256) void out_kernel(const float* __restrict__ a,
                                                  const float* __restrict__ c,
                                                  f32x4* __restrict__ out) {
    const f32x4* c4 = (const f32x4*)c;
    size_t base = (size_t)blockIdx.x * 1024 + threadIdx.x;
#pragma unroll
    for (int q = 0; q < 4; ++q) {
        size_t idx = base + q * 256;
        int i = (int)(idx >> 11);
        int j4 = (int)(idx & 2047);
        f32x4 r = c4[j4] + a[i];
        out[idx] = r;
    }
}

extern "C" void kernel_launch(void* const* d_in, const int* in_sizes, int n_in,
                              void* d_out, int out_size, void* d_ws, size_t ws_size,
                              hipStream_t stream) {
    const float* x    = (const float*)d_in[0];
    const int*   ei   = (const int*)d_in[1];
    const float* W1   = (const float*)d_in[2];
    const float* b1   = (const float*)d_in[3];
    const float* W2   = (const float*)d_in[4];
    const float* b2   = (const float*)d_in[5];
    const float* Wout = (const float*)d_in[6];
    const float* bout = (const float*)d_in[7];
    const float* We   = (const float*)d_in[8];
    const float* bedge= (const float*)d_in[9];
    const int* src = ei;
    const int* dst = ei + NE;

    // workspace
    int* cnt     = (int*)d_ws;                    // 8192
    int* bucket  = cnt + NN;                      // 8192*128
    float* u     = (float*)(bucket + NN * BCAP);  // 128
    float* v     = u + DIM;                       // 128
    float* beta  = v + DIM;                       // 2 (pad 16)
    float* g1    = beta + 16;                     // 8192*128
    float* s2    = g1 + NN * DIM;                 // 8192*128
    float* g2    = s2 + NN * DIM;                 // 8192*128
    float* av    = g2 + NN * DIM;                 // 8192
    float* cv    = av + NN;                       // 8192

    float* out = (float*)d_out;

    zero_kernel<<<32, 256, 0, stream>>>(cnt);
    fused_pre<<<1281, 256, 0, stream>>>(x, W1, (f32x4*)g1, src, dst, cnt, bucket,
                                        Wout, bout, We, bedge, u, v, beta);
    gather_scale<<<NN / 4, 256, 0, stream>>>(g1, cnt, bucket, b1, (f32x2*)s2);
    gemm_mid<<<NN / 32, 256, 0, stream>>>(s2, W2, (f32x4*)g2);
    agg_head<<<NN / 4, 256, 0, stream>>>(g2, cnt, bucket, b2, u, v, beta, av, cv);
    out_kernel<<<(NN * NN / 4) / 1024, 256, 0, stream>>>(av, cv, (f32x4*)out);
}

// Round 10
// 109.108 us; speedup vs baseline: 1.1104x; 1.0082x over previous
//
#include <hip/hip_runtime.h>

#define NN 8192      // nodes
#define NE 262144    // edges
#define DIM 128
#define BCAP 128     // bucket capacity (deg ~ Poisson(32); P(deg>128) ~ 0)

typedef float f32x4 __attribute__((ext_vector_type(4)));
typedef float f32x2 __attribute__((ext_vector_type(2)));

__device__ __forceinline__ float4 f4fma(float s, float4 w, float4 acc) {
    acc.x = fmaf(s, w.x, acc.x);
    acc.y = fmaf(s, w.y, acc.y);
    acc.z = fmaf(s, w.z, acc.z);
    acc.w = fmaf(s, w.w, acc.w);
    return acc;
}
__device__ __forceinline__ float f4dot(float4 a, float4 b) {
    return fmaf(a.x, b.x, fmaf(a.y, b.y, fmaf(a.z, b.z, a.w * b.w)));
}

// ---------------- K1: zero cnt ----------------
__global__ __launch_bounds__(256) void zero_kernel(int* __restrict__ cnt) {
    cnt[blockIdx.x * 256 + threadIdx.x] = 0;
}

// ---------------- K2: fused [gemm_pre_raw (blk 0-255)] | [scatter (blk 256-1279)] | [uv (blk 1280)] ----------------
__global__ __launch_bounds__(256) void fused_pre(const float* __restrict__ X,
                                                 const float* __restrict__ W,
                                                 float* __restrict__ G,
                                                 const int* __restrict__ src,
                                                 const int* __restrict__ dst,
                                                 int* __restrict__ cnt,
                                                 int* __restrict__ bucket,
                                                 const float* __restrict__ Wout,
                                                 const float* __restrict__ bout,
                                                 const float* __restrict__ we,
                                                 const float* __restrict__ bedge,
                                                 float* __restrict__ u,
                                                 float* __restrict__ v,
                                                 float* __restrict__ beta) {
    __shared__ float4 Wl[128 * 32];  // 64KB (gemm branch only)
    __shared__ float4 Xl[32 * 32];   // 16KB (gemm); overlaid as red[] by uv branch
    int tid = threadIdx.x;
    int bid = blockIdx.x;

    if (bid < 256) {
        // ---- raw GEMM: G1[r] = (x @ W1)[r] (dinv commuted into gather) ----
        int rbase = bid * 32;
        const float4* W4 = (const float4*)W;
#pragma unroll
        for (int i = 0; i < 16; ++i) Wl[i * 256 + tid] = W4[i * 256 + tid];
        const float4* X4 = (const float4*)(X + rbase * DIM);
#pragma unroll
        for (int i = 0; i < 4; ++i) Xl[i * 256 + tid] = X4[i * 256 + tid];
        __syncthreads();

        int tx = tid & 31;
        int ty = tid >> 5;
        float4 acc[4];
#pragma unroll
        for (int i = 0; i < 4; ++i) acc[i] = make_float4(0.f, 0.f, 0.f, 0.f);

        for (int k4 = 0; k4 < 32; ++k4) {
            float4 w0 = Wl[(k4 * 4 + 0) * 32 + tx];
            float4 w1 = Wl[(k4 * 4 + 1) * 32 + tx];
            float4 w2 = Wl[(k4 * 4 + 2) * 32 + tx];
            float4 w3 = Wl[(k4 * 4 + 3) * 32 + tx];
#pragma unroll
            for (int i = 0; i < 4; ++i) {
                float4 xv = Xl[(ty * 4 + i) * 32 + k4];
                acc[i] = f4fma(xv.x, w0, acc[i]);
                acc[i] = f4fma(xv.y, w1, acc[i]);
                acc[i] = f4fma(xv.z, w2, acc[i]);
                acc[i] = f4fma(xv.w, w3, acc[i]);
            }
        }
        float4* G4 = (float4*)G;
#pragma unroll
        for (int i = 0; i < 4; ++i) {
            int r = rbase + ty * 4 + i;
            G4[r * 32 + tx] = acc[i];   // plain store: keep table cacheable
        }
        return;
    }
    if (bid < 1280) {
        // ---- scatter edges into buckets; cnt ends as indegree ----
        int e = (bid - 256) * 256 + tid;
        int d = dst[e];
        int p = atomicAdd(&cnt[d], 1);
        if (p < BCAP) bucket[(d << 7) + p] = src[e];
        return;
    }
    // ---- block 1280: u/v/beta ----
    float* red = (float*)Xl;
    int k = tid;
    if (k < DIM) {
        const float4* W4o = (const float4*)(Wout + (k << 7));
        const float4* we4 = (const float4*)we;
        float su = 0.f, sv = 0.f;
#pragma unroll
        for (int j = 0; j < 32; ++j) {
            float4 w = W4o[j];
            su += f4dot(w, we4[j]);
            sv += f4dot(w, we4[32 + j]);
        }
        u[k] = su;
        v[k] = sv;
    }
    red[k] = (k < DIM) ? bout[k] * we[k] : 0.f;
    __syncthreads();
    for (int off = 128; off >= 1; off >>= 1) {
        if (k < off) red[k] += red[k + off];
        __syncthreads();
    }
    float b0 = red[0];
    __syncthreads();
    red[k] = (k < DIM) ? bout[k] * we[DIM + k] : 0.f;
    __syncthreads();
    for (int off = 128; off >= 1; off >>= 1) {
        if (k < off) red[k] += red[k + off];
        __syncthreads();
    }
    if (k == 0) {
        beta[0] = b0 + bedge[0];
        beta[1] = red[0];
    }
}

// ---------------- F2: gather(G1raw, per-edge dinv) + S2 = dv*relu(dv*y + b1) ----------------
__global__ __launch_bounds__(256) void gather_scale(const float* __restrict__ G1,
                                                    const int* __restrict__ cnt,
                                                    const int* __restrict__ bucket,
                                                    const float* __restrict__ b1,
                                                    float* __restrict__ S2) {
    int node = blockIdx.x * 4 + (threadIdx.x >> 6);
    int lane = threadIdx.x & 63;
    const float2* G12 = (const float2*)G1;

    int degree = cnt[node];
    float dv = rsqrtf((float)(degree + 1));
    int deg = min(degree, BCAP);
    int i0 = bucket[(node << 7) + lane];
    int i1 = bucket[(node << 7) + 64 + lane];

    float2 selfv = G12[node * 64 + lane];
    float ax = selfv.x * dv, ay = selfv.y * dv;   // self: src dinv = own dv
    float px[8], py[8];
#pragma unroll
    for (int k = 0; k < 8; ++k) { px[k] = 0.f; py[k] = 0.f; }

    int d8 = deg & ~7;
    for (int e = 0; e < d8; e += 8) {
        int s[8];
#pragma unroll
        for (int k = 0; k < 8; ++k) s[k] = __shfl((e + k) >= 64 ? i1 : i0, (e + k) & 63);
#pragma unroll
        for (int k = 0; k < 8; ++k) {
            int ck = cnt[s[k]];
            float2 t = G12[s[k] * 64 + lane];
            float w = rsqrtf((float)(ck + 1));
            px[k] = fmaf(t.x, w, px[k]);
            py[k] = fmaf(t.y, w, py[k]);
        }
    }
    for (int e = d8; e < deg; ++e) {
        int s = __shfl(e >= 64 ? i1 : i0, e & 63);
        int ck = cnt[s];
        float2 t = G12[s * 64 + lane];
        float w = rsqrtf((float)(ck + 1));
        ax = fmaf(t.x, w, ax);
        ay = fmaf(t.y, w, ay);
    }
    float yx = ax + ((px[0] + px[1]) + (px[2] + px[3])) + ((px[4] + px[5]) + (px[6] + px[7]));
    float yy = ay + ((py[0] + py[1]) + (py[2] + py[3])) + ((py[4] + py[5]) + (py[6] + py[7]));

    const float2* B2 = (const float2*)b1;
    float2 bb = B2[lane];
    float2 o;
    o.x = fmaxf(fmaf(yx, dv, bb.x), 0.f) * dv;
    o.y = fmaxf(fmaf(yy, dv, bb.y), 0.f) * dv;
    ((float2*)S2)[node * 64 + lane] = o;          // plain store
}

// ---------------- F3: G2 = S2 @ W2 (raw), plain store ----------------
__global__ __launch_bounds__(256) void gemm_mid(const float* __restrict__ X,
                                                const float* __restrict__ W,
                                                float* __restrict__ G) {
    __shared__ float4 Wl[128 * 32];
    __shared__ float4 Xl[32 * 32];
    int tid = threadIdx.x;
    int rbase = blockIdx.x * 32;

    const float4* W4 = (const float4*)W;
#pragma unroll
    for (int i = 0; i < 16; ++i) Wl[i * 256 + tid] = W4[i * 256 + tid];
    const float4* X4 = (const float4*)(X + rbase * DIM);
#pragma unroll
    for (int i = 0; i < 4; ++i) Xl[i * 256 + tid] = X4[i * 256 + tid];
    __syncthreads();

    int tx = tid & 31;
    int ty = tid >> 5;
    float4 acc[4];
#pragma unroll
    for (int i = 0; i < 4; ++i) acc[i] = make_float4(0.f, 0.f, 0.f, 0.f);

    for (int k4 = 0; k4 < 32; ++k4) {
        float4 w0 = Wl[(k4 * 4 + 0) * 32 + tx];
        float4 w1 = Wl[(k4 * 4 + 1) * 32 + tx];
        float4 w2 = Wl[(k4 * 4 + 2) * 32 + tx];
        float4 w3 = Wl[(k4 * 4 + 3) * 32 + tx];
#pragma unroll
        for (int i = 0; i < 4; ++i) {
            float4 xv = Xl[(ty * 4 + i) * 32 + k4];
            acc[i] = f4fma(xv.x, w0, acc[i]);
            acc[i] = f4fma(xv.y, w1, acc[i]);
            acc[i] = f4fma(xv.z, w2, acc[i]);
            acc[i] = f4fma(xv.w, w3, acc[i]);
        }
    }

    float4* G4 = (float4*)G;
#pragma unroll
    for (int i = 0; i < 4; ++i) {
        int r = rbase + ty * 4 + i;
        G4[r * 32 + tx] = acc[i];    // plain store
    }
}

// ---------------- F4: gather(G2) + head -> a, c (ILP-8) ----------------
__global__ __launch_bounds__(256) void agg_head(const float* __restrict__ G2,
                                                const int* __restrict__ cnt,
                                                const int* __restrict__ bucket,
                                                const float* __restrict__ b2,
                                                const float* __restrict__ u,
                                                const float* __restrict__ v,
                                                const float* __restrict__ beta,
                                                float* __restrict__ a,
                                                float* __restrict__ c) {
    int node = blockIdx.x * 4 + (threadIdx.x >> 6);
    int lane = threadIdx.x & 63;
    const float2* G22 = (const float2*)G2;

    int degree = cnt[node];
    float dv = rsqrtf((float)(degree + 1));
    int deg = min(degree, BCAP);
    int i0 = bucket[(node << 7) + lane];
    int i1 = bucket[(node << 7) + 64 + lane];

    float2 selfv = G22[node * 64 + lane];
    float ax = selfv.x, ay = selfv.y;
    float px[8], py[8];
#pragma unroll
    for (int k = 0; k < 8; ++k) { px[k] = 0.f; py[k] = 0.f; }

    int d8 = deg & ~7;
    for (int e = 0; e < d8; e += 8) {
        int s[8];
#pragma unroll
        for (int k = 0; k < 8; ++k) s[k] = __shfl((e + k) >= 64 ? i1 : i0, (e + k) & 63);
#pragma unroll
        for (int k = 0; k < 8; ++k) {
            float2 t = G22[s[k] * 64 + lane];
            px[k] += t.x;
            py[k] += t.y;
        }
    }
    for (int e = d8; e < deg; ++e) {
        int s = __shfl(e >= 64 ? i1 : i0, e & 63);
        float2 t = G22[s * 64 + lane];
        ax += t.x;
        ay += t.y;
    }
    float yx = ax + ((px[0] + px[1]) + (px[2] + px[3])) + ((px[4] + px[5]) + (px[6] + px[7]));
    float yy = ay + ((py[0] + py[1]) + (py[2] + py[3])) + ((py[4] + py[5]) + (py[6] + py[7]));

    const float2* B2 = (const float2*)b2;
    float2 bb = B2[lane];
    float h0 = fmaxf(fmaf(yx, dv, bb.x), 0.f);
    float h1 = fmaxf(fmaf(yy, dv, bb.y), 0.f);

    float2 uu = ((const float2*)u)[lane];
    float2 vv = ((const float2*)v)[lane];
    float pa = h0 * uu.x + h1 * uu.y;
    float pc = h0 * vv.x + h1 * vv.y;
#pragma unroll
    for (int off = 32; off >= 1; off >>= 1) {
        pa += __shfl_xor(pa, off);
        pc += __shfl_xor(pc, off);
    }
    if (lane == 0) {
        a[node] = pa + beta[0];
        c[node] = pc + beta[1];
    }
}

// ---------------- out[i][j] = a[i] + c[j] (plain stores — R8-proven) ----------------
__global__ __launch_bounds__(256) void out_kernel(const float* __restrict__ a,
                                                  const float* __restrict__ c,
                                                  f32x4* __restrict__ out) {
    const f32x4* c4 = (const f32x4*)c;
    size_t base = (size_t)blockIdx.x * 1024 + threadIdx.x;
#pragma unroll
    for (int q = 0; q < 4; ++q) {
        size_t idx = base + q * 256;
        int i = (int)(idx >> 11);
        int j4 = (int)(idx & 2047);
        f32x4 r = c4[j4] + a[i];
        out[idx] = r;
    }
}

extern "C" void kernel_launch(void* const* d_in, const int* in_sizes, int n_in,
                              void* d_out, int out_size, void* d_ws, size_t ws_size,
                              hipStream_t stream) {
    const float* x    = (const float*)d_in[0];
    const int*   ei   = (const int*)d_in[1];
    const float* W1   = (const float*)d_in[2];
    const float* b1   = (const float*)d_in[3];
    const float* W2   = (const float*)d_in[4];
    const float* b2   = (const float*)d_in[5];
    const float* Wout = (const float*)d_in[6];
    const float* bout = (const float*)d_in[7];
    const float* We   = (const float*)d_in[8];
    const float* bedge= (const float*)d_in[9];
    const int* src = ei;
    const int* dst = ei + NE;

    // workspace
    int* cnt     = (int*)d_ws;                    // 8192
    int* bucket  = cnt + NN;                      // 8192*128
    float* u     = (float*)(bucket + NN * BCAP);  // 128
    float* v     = u + DIM;                       // 128
    float* beta  = v + DIM;                       // 2 (pad 16)
    float* g1    = beta + 16;                     // 8192*128
    float* s2    = g1 + NN * DIM;                 // 8192*128
    float* g2    = s2 + NN * DIM;                 // 8192*128
    float* av    = g2 + NN * DIM;                 // 8192
    float* cv    = av + NN;                       // 8192

    float* out = (float*)d_out;

    zero_kernel<<<32, 256, 0, stream>>>(cnt);
    fused_pre<<<1281, 256, 0, stream>>>(x, W1, g1, src, dst, cnt, bucket,
                                        Wout, bout, We, bedge, u, v, beta);
    gather_scale<<<NN / 4, 256, 0, stream>>>(g1, cnt, bucket, b1, s2);
    gemm_mid<<<NN / 32, 256, 0, stream>>>(s2, W2, g2);
    agg_head<<<NN / 4, 256, 0, stream>>>(g2, cnt, bucket, b2, u, v, beta, av, cv);
    out_kernel<<<(NN * NN / 4) / 1024, 256, 0, stream>>>(av, cv, (f32x4*)out);
}